// Round 1
// baseline (815.674 us; speedup 1.0000x reference)
//
#include <hip/hip_runtime.h>
#include <hip/hip_bf16.h>

#define N_NODES 100000
#define IN_CH 128
#define HID_CH 64
#define OUT_CH 32

// ---------------- degree / normalization ----------------

__global__ void k_deg_init(float* __restrict__ deg, int N) {
    int i = blockIdx.x * blockDim.x + threadIdx.x;
    if (i < N) deg[i] = 1.0f;  // self-loop
}

__global__ void k_deg_count(const int* __restrict__ dst, float* __restrict__ deg, int E) {
    int e = blockIdx.x * blockDim.x + threadIdx.x;
    if (e < E) atomicAdd(&deg[dst[e]], 1.0f);
}

__global__ void k_rsqrt_inplace(float* __restrict__ deg, int N) {
    int i = blockIdx.x * blockDim.x + threadIdx.x;
    if (i < N) deg[i] = rsqrtf(deg[i]);  // deg >= 1 always (self-loop)
}

// ---------------- dense transform: H[N,OUT] = act(X[N,IN]) @ W[IN,OUT] ----------------
// One thread per output element; W staged in LDS; ROWS=256/OUT rows per block.

template <int IN, int OUT, bool RELU_IN>
__global__ __launch_bounds__(256) void k_matmul(const float* __restrict__ X,
                                                const float* __restrict__ W,
                                                float* __restrict__ H, int N) {
    constexpr int ROWS = 256 / OUT;
    __shared__ float sW[IN * OUT];
    __shared__ float sX[ROWS][IN];

    for (int i = threadIdx.x; i < IN * OUT; i += 256) sW[i] = W[i];

    const int row0 = blockIdx.x * ROWS;
    for (int i = threadIdx.x; i < ROWS * IN; i += 256) {
        int r = i / IN, k = i % IN;
        int row = row0 + r;
        float v = (row < N) ? X[(long long)row * IN + k] : 0.0f;
        if (RELU_IN) v = fmaxf(v, 0.0f);
        sX[r][k] = v;
    }
    __syncthreads();

    const int r = threadIdx.x / OUT;
    const int c = threadIdx.x % OUT;
    const int row = row0 + r;
    if (row < N) {
        float acc = 0.0f;
#pragma unroll
        for (int k = 0; k < IN; ++k) acc += sX[r][k] * sW[k * OUT + c];
        H[(long long)row * OUT + c] = acc;
    }
}

// ---------------- self-loop + bias init: Z[i,c] = b[c] + dis[i]^2 * H[i,c] ----------------

template <int C>
__global__ void k_init_z(const float* __restrict__ H, const float* __restrict__ dis,
                         const float* __restrict__ b, float* __restrict__ Z, int N) {
    int i = blockIdx.x * blockDim.x + threadIdx.x;
    if (i < N * C) {
        int n = i / C, c = i % C;
        float d = dis[n];
        Z[i] = b[c] + d * d * H[i];
    }
}

// ---------------- edge scatter: Z[dst,c] += dis[src]*dis[dst]*H[src,c] ----------------
// Thread layout: channel is fastest dim -> 64-lane wave covers 1 edge (C=64) or 2 edges
// (C=32); gather reads and atomic writes are coalesced contiguous runs.

template <int C>
__global__ void k_scatter(const int* __restrict__ src, const int* __restrict__ dst,
                          const float* __restrict__ dis, const float* __restrict__ H,
                          float* __restrict__ Z, int total /* E*C */) {
    int i = blockIdx.x * blockDim.x + threadIdx.x;
    if (i >= total) return;
    int e = i / C;
    int c = i % C;
    int s = src[e];
    int d = dst[e];
    float nrm = dis[s] * dis[d];
    atomicAdd(&Z[(long long)d * C + c], nrm * H[(long long)s * C + c]);
}

extern "C" void kernel_launch(void* const* d_in, const int* in_sizes, int n_in,
                              void* d_out, int out_size, void* d_ws, size_t ws_size,
                              hipStream_t stream) {
    const float* x  = (const float*)d_in[0];
    const int*   ei = (const int*)d_in[1];
    const float* W1 = (const float*)d_in[2];
    const float* b1 = (const float*)d_in[3];
    const float* W2 = (const float*)d_in[4];
    const float* b2 = (const float*)d_in[5];
    float* out = (float*)d_out;

    const int N = in_sizes[0] / IN_CH;
    const int E = in_sizes[1] / 2;
    const int* esrc = ei;
    const int* edst = ei + E;

    // workspace layout (floats): dis[N] | h1[N*HID] | z1[N*HID]; h2 aliases h1
    float* dis = (float*)d_ws;
    float* h1  = dis + N;
    float* z1  = h1 + (long long)N * HID_CH;
    float* h2  = h1;  // h1 dead after layer-1 scatter

    const int B = 256;

    // degree + normalization
    k_deg_init<<<(N + B - 1) / B, B, 0, stream>>>(dis, N);
    k_deg_count<<<(E + B - 1) / B, B, 0, stream>>>(edst, dis, E);
    k_rsqrt_inplace<<<(N + B - 1) / B, B, 0, stream>>>(dis, N);

    // layer 1: h1 = x @ W1
    {
        constexpr int ROWS = 256 / HID_CH;
        k_matmul<IN_CH, HID_CH, false><<<(N + ROWS - 1) / ROWS, B, 0, stream>>>(x, W1, h1, N);
    }
    // z1 = b1 + dis^2 * h1, then scatter edges
    k_init_z<HID_CH><<<((long long)N * HID_CH + B - 1) / B, B, 0, stream>>>(h1, dis, b1, z1, N);
    {
        int total = E * HID_CH;
        k_scatter<HID_CH><<<(total + B - 1) / B, B, 0, stream>>>(esrc, edst, dis, h1, z1, total);
    }

    // layer 2: h2 = relu(z1) @ W2
    {
        constexpr int ROWS = 256 / OUT_CH;
        k_matmul<HID_CH, OUT_CH, true><<<(N + ROWS - 1) / ROWS, B, 0, stream>>>(z1, W2, h2, N);
    }
    // out = b2 + dis^2 * h2, then scatter edges
    k_init_z<OUT_CH><<<((long long)N * OUT_CH + B - 1) / B, B, 0, stream>>>(h2, dis, b2, out, N);
    {
        int total = E * OUT_CH;
        k_scatter<OUT_CH><<<(total + B - 1) / B, B, 0, stream>>>(esrc, edst, dis, h2, out, total);
    }
}

// Round 2
// 585.947 us; speedup vs baseline: 1.3921x; 1.3921x over previous
//
#include <hip/hip_runtime.h>
#include <hip/hip_bf16.h>

#define IN_CH 128
#define HID_CH 64
#define OUT_CH 32

// ---------------- CSR build ----------------

__global__ void k_hist(const int* __restrict__ dst, int* __restrict__ counts, int E) {
    int e = blockIdx.x * blockDim.x + threadIdx.x;
    if (e < E) atomicAdd(&counts[dst[e]], 1);
}

// Per-1024-chunk exclusive scan of counts -> rowptr (chunk-local), block totals out.
// Also computes dis[i] = rsqrt(indeg + 1) since we're reading counts anyway.
__global__ __launch_bounds__(256) void k_scan_a(const int* __restrict__ counts,
                                                int* __restrict__ rowptr,
                                                int* __restrict__ blocksums,
                                                float* __restrict__ dis, int N) {
    __shared__ int sT[256];
    const int base = blockIdx.x * 1024;
    int v[4];
    int tsum = 0;
#pragma unroll
    for (int t = 0; t < 4; ++t) {
        int i = base + threadIdx.x * 4 + t;
        int c = (i < N) ? counts[i] : 0;
        if (i < N) dis[i] = rsqrtf((float)(c + 1));
        v[t] = tsum;  // exclusive within thread
        tsum += c;
    }
    sT[threadIdx.x] = tsum;
    __syncthreads();
    // Hillis-Steele inclusive scan over 256 thread sums
    for (int off = 1; off < 256; off <<= 1) {
        int val = (threadIdx.x >= off) ? sT[threadIdx.x - off] : 0;
        __syncthreads();
        sT[threadIdx.x] += val;
        __syncthreads();
    }
    int texcl = (threadIdx.x == 0) ? 0 : sT[threadIdx.x - 1];
#pragma unroll
    for (int t = 0; t < 4; ++t) {
        int i = base + threadIdx.x * 4 + t;
        if (i < N) rowptr[i] = texcl + v[t];
    }
    if (threadIdx.x == 255) blocksums[blockIdx.x] = sT[255];
}

// Single-block exclusive scan of block sums (nb <= 256).
__global__ __launch_bounds__(256) void k_scan_b(int* __restrict__ blocksums, int nb) {
    __shared__ int s[256];
    int v = (threadIdx.x < nb) ? blocksums[threadIdx.x] : 0;
    s[threadIdx.x] = v;
    __syncthreads();
    for (int off = 1; off < 256; off <<= 1) {
        int val = (threadIdx.x >= off) ? s[threadIdx.x - off] : 0;
        __syncthreads();
        s[threadIdx.x] += val;
        __syncthreads();
    }
    if (threadIdx.x < nb)
        blocksums[threadIdx.x] = (threadIdx.x == 0) ? 0 : s[threadIdx.x - 1];
}

// Add chunk offsets; zero cursor (reuses counts); rowptr[N] = E.
__global__ void k_scan_c(int* __restrict__ rowptr, const int* __restrict__ blocksums,
                         int* __restrict__ cursor, int N, int E) {
    int i = blockIdx.x * blockDim.x + threadIdx.x;
    if (i < N) {
        rowptr[i] += blocksums[i >> 10];
        cursor[i] = 0;
    }
    if (i == 0) rowptr[N] = E;
}

__global__ void k_fill(const int* __restrict__ src, const int* __restrict__ dst,
                       const int* __restrict__ rowptr, int* __restrict__ cursor,
                       int* __restrict__ col, int E) {
    int e = blockIdx.x * blockDim.x + threadIdx.x;
    if (e < E) {
        int d = dst[e];
        int p = rowptr[d] + atomicAdd(&cursor[d], 1);
        col[p] = src[e];
    }
}

// ---------------- dense transform: H[N,OUT] = act(X[N,IN]) @ W[IN,OUT] ----------------

template <int IN, int OUT, bool RELU_IN>
__global__ __launch_bounds__(256) void k_matmul(const float* __restrict__ X,
                                                const float* __restrict__ W,
                                                float* __restrict__ H, int N) {
    constexpr int ROWS = 256 / OUT;
    __shared__ float sW[IN * OUT];
    __shared__ float sX[ROWS][IN];

    for (int i = threadIdx.x; i < IN * OUT; i += 256) sW[i] = W[i];

    const int row0 = blockIdx.x * ROWS;
    for (int i = threadIdx.x; i < ROWS * IN; i += 256) {
        int r = i / IN, k = i % IN;
        int row = row0 + r;
        float v = (row < N) ? X[(long long)row * IN + k] : 0.0f;
        if (RELU_IN) v = fmaxf(v, 0.0f);
        sX[r][k] = v;
    }
    __syncthreads();

    const int r = threadIdx.x / OUT;
    const int c = threadIdx.x % OUT;
    const int row = row0 + r;
    if (row < N) {
        float acc = 0.0f;
#pragma unroll
        for (int k = 0; k < IN; ++k) acc += sX[r][k] * sW[k * OUT + c];
        H[(long long)row * OUT + c] = acc;
    }
}

// ---------------- CSR aggregation (gather, no atomics) ----------------
// z[d,c] = b[c] + dis[d] * ( sum_{e: dst=d} dis[src_e]*h[src_e,c] + dis[d]*h[d,c] )

__global__ __launch_bounds__(256) void k_agg64(const float* __restrict__ h,
                                               const int* __restrict__ rowptr,
                                               const int* __restrict__ col,
                                               const float* __restrict__ dis,
                                               const float* __restrict__ b,
                                               float* __restrict__ z, int N) {
    const int wave = (blockIdx.x * 256 + threadIdx.x) >> 6;
    const int lane = threadIdx.x & 63;
    if (wave >= N) return;
    const int row = wave;
    const float dr = dis[row];
    float acc = dr * h[(long long)row * 64 + lane];  // self-loop
    int j = rowptr[row];
    const int end = rowptr[row + 1];
    for (; j + 1 < end; j += 2) {  // unroll x2 for memory-level parallelism
        int s0 = col[j], s1 = col[j + 1];
        float a0 = dis[s0] * h[(long long)s0 * 64 + lane];
        float a1 = dis[s1] * h[(long long)s1 * 64 + lane];
        acc += a0 + a1;
    }
    if (j < end) {
        int s0 = col[j];
        acc += dis[s0] * h[(long long)s0 * 64 + lane];
    }
    z[(long long)row * 64 + lane] = b[lane] + dr * acc;
}

// 32 channels: one wave per row; lane halves process even/odd edges, shuffle-combine.
__global__ __launch_bounds__(256) void k_agg32(const float* __restrict__ h,
                                               const int* __restrict__ rowptr,
                                               const int* __restrict__ col,
                                               const float* __restrict__ dis,
                                               const float* __restrict__ b,
                                               float* __restrict__ out, int N) {
    const int wave = (blockIdx.x * 256 + threadIdx.x) >> 6;
    const int lane = threadIdx.x & 63;
    if (wave >= N) return;
    const int row = wave;
    const int c = lane & 31;
    const int half = lane >> 5;
    const float dr = dis[row];
    float acc = half ? 0.0f : dr * h[(long long)row * 32 + c];  // self-loop once
    const int start = rowptr[row], end = rowptr[row + 1];
    for (int j = start + half; j < end; j += 2) {
        int s = col[j];
        acc += dis[s] * h[(long long)s * 32 + c];
    }
    acc += __shfl_down(acc, 32);
    if (!half) out[(long long)row * 32 + c] = b[c] + dr * acc;
}

extern "C" void kernel_launch(void* const* d_in, const int* in_sizes, int n_in,
                              void* d_out, int out_size, void* d_ws, size_t ws_size,
                              hipStream_t stream) {
    const float* x  = (const float*)d_in[0];
    const int*   ei = (const int*)d_in[1];
    const float* W1 = (const float*)d_in[2];
    const float* b1 = (const float*)d_in[3];
    const float* W2 = (const float*)d_in[4];
    const float* b2 = (const float*)d_in[5];
    float* out = (float*)d_out;

    const int N = in_sizes[0] / IN_CH;
    const int E = in_sizes[1] / 2;
    const int* esrc = ei;
    const int* edst = ei + E;

    // workspace layout (all 4-byte elems, regions padded to 16-elem multiples)
    int* counts    = (int*)d_ws;                       // N
    int* rowptr    = counts + ((N + 15) & ~15);        // N+1 (padded)
    int* blocksums = rowptr + (((N + 1) + 15) & ~15);  // 256
    int* col       = blocksums + 256;                  // E
    float* dis     = (float*)(col + ((E + 15) & ~15)); // N
    float* h1      = dis + ((N + 15) & ~15);           // N*64
    float* z1      = h1 + (long long)N * HID_CH;       // N*64
    float* h2      = h1;                               // h1 dead after agg64

    const int B = 256;
    const int nb = (N + 1023) / 1024;  // scan chunks (must be <= 256; N=100k -> 98)

    // ---- CSR build + normalization ----
    hipMemsetAsync(counts, 0, (size_t)N * sizeof(int), stream);
    k_hist<<<(E + B - 1) / B, B, 0, stream>>>(edst, counts, E);
    k_scan_a<<<nb, B, 0, stream>>>(counts, rowptr, blocksums, dis, N);
    k_scan_b<<<1, B, 0, stream>>>(blocksums, nb);
    k_scan_c<<<(N + B - 1) / B, B, 0, stream>>>(rowptr, blocksums, counts, N, E);
    k_fill<<<(E + B - 1) / B, B, 0, stream>>>(esrc, edst, rowptr, counts, col, E);

    // ---- layer 1 ----
    {
        constexpr int ROWS = 256 / HID_CH;
        k_matmul<IN_CH, HID_CH, false><<<(N + ROWS - 1) / ROWS, B, 0, stream>>>(x, W1, h1, N);
    }
    k_agg64<<<(N * 64 + B - 1) / B, B, 0, stream>>>(h1, rowptr, col, dis, b1, z1, N);

    // ---- layer 2 ----
    {
        constexpr int ROWS = 256 / OUT_CH;
        k_matmul<HID_CH, OUT_CH, true><<<(N + ROWS - 1) / ROWS, B, 0, stream>>>(z1, W2, h2, N);
    }
    k_agg32<<<(N * 64 + B - 1) / B, B, 0, stream>>>(h2, rowptr, col, dis, b2, out, N);
}

// Round 3
// 437.967 us; speedup vs baseline: 1.8624x; 1.3379x over previous
//
#include <hip/hip_runtime.h>
#include <hip/hip_bf16.h>

#define IN_CH 128
#define HID_CH 64
#define OUT_CH 32
#define EPB 2048  // edges per partition block
#define MAXB 512  // max buckets (N <= 131072)

// ---------------- single-pass radix partition by dst>>8 ----------------
// pairs[b*cap + slot] = (src<<8) | (dst&255); gcursor[b] ends as bucket count.

__global__ __launch_bounds__(256) void k_partition(const int* __restrict__ src,
                                                   const int* __restrict__ dst,
                                                   int* __restrict__ gcursor,
                                                   unsigned* __restrict__ pairs,
                                                   int E, int nbk, int cap) {
    __shared__ int lhist[MAXB];
    __shared__ int lbase[MAXB];
    __shared__ int lcur[MAXB];
    const int tid = threadIdx.x;
    for (int b = tid; b < nbk; b += 256) { lhist[b] = 0; lcur[b] = 0; }
    __syncthreads();
    int s[8], d[8];
    const int e0 = blockIdx.x * EPB;
#pragma unroll
    for (int j = 0; j < 8; ++j) {
        int e = e0 + j * 256 + tid;
        if (e < E) {
            s[j] = src[e];
            d[j] = dst[e];
            atomicAdd(&lhist[d[j] >> 8], 1);
        } else {
            d[j] = -1;
        }
    }
    __syncthreads();
    for (int b = tid; b < nbk; b += 256)
        lbase[b] = lhist[b] ? atomicAdd(&gcursor[b], lhist[b]) : 0;
    __syncthreads();
#pragma unroll
    for (int j = 0; j < 8; ++j) {
        if (d[j] >= 0) {
            int b = d[j] >> 8;
            int loc = atomicAdd(&lcur[b], 1);
            int idx = lbase[b] + loc;
            if (idx < cap)  // 20-sigma margin; guard keeps memory safe regardless
                pairs[(long long)b * cap + idx] = ((unsigned)s[j] << 8) | (unsigned)(d[j] & 255);
        }
    }
}

// per-bucket row counts (non-atomic global write; buckets own disjoint rows) + dis
__global__ __launch_bounds__(256) void k_bucket_counts(const unsigned* __restrict__ pairs,
                                                       const int* __restrict__ gcursor,
                                                       int* __restrict__ counts,
                                                       float* __restrict__ dis,
                                                       int cap, int N) {
    __shared__ int lc[256];
    const int b = blockIdx.x, tid = threadIdx.x;
    lc[tid] = 0;
    __syncthreads();
    const int cnt = min(gcursor[b], cap);
    const unsigned* p = pairs + (long long)b * cap;
    for (int i = tid; i < cnt; i += 256) atomicAdd(&lc[p[i] & 255], 1);
    __syncthreads();
    int row = b * 256 + tid;
    if (row < N) {
        counts[row] = lc[tid];
        dis[row] = rsqrtf((float)(lc[tid] + 1));  // +1 self-loop
    }
}

// ---------------- rowptr scan ----------------

__global__ __launch_bounds__(256) void k_scan_a(const int* __restrict__ counts,
                                                int* __restrict__ rowptr,
                                                int* __restrict__ blocksums, int N) {
    __shared__ int sT[256];
    const int base = blockIdx.x * 1024;
    int v[4];
    int tsum = 0;
#pragma unroll
    for (int t = 0; t < 4; ++t) {
        int i = base + threadIdx.x * 4 + t;
        int c = (i < N) ? counts[i] : 0;
        v[t] = tsum;
        tsum += c;
    }
    sT[threadIdx.x] = tsum;
    __syncthreads();
    for (int off = 1; off < 256; off <<= 1) {
        int val = (threadIdx.x >= off) ? sT[threadIdx.x - off] : 0;
        __syncthreads();
        sT[threadIdx.x] += val;
        __syncthreads();
    }
    int texcl = (threadIdx.x == 0) ? 0 : sT[threadIdx.x - 1];
#pragma unroll
    for (int t = 0; t < 4; ++t) {
        int i = base + threadIdx.x * 4 + t;
        if (i < N) rowptr[i] = texcl + v[t];
    }
    if (threadIdx.x == 255) blocksums[blockIdx.x] = sT[255];
}

__global__ __launch_bounds__(256) void k_scan_b(int* __restrict__ blocksums, int nb) {
    __shared__ int s[256];
    int v = (threadIdx.x < nb) ? blocksums[threadIdx.x] : 0;
    s[threadIdx.x] = v;
    __syncthreads();
    for (int off = 1; off < 256; off <<= 1) {
        int val = (threadIdx.x >= off) ? s[threadIdx.x - off] : 0;
        __syncthreads();
        s[threadIdx.x] += val;
        __syncthreads();
    }
    if (threadIdx.x < nb)
        blocksums[threadIdx.x] = (threadIdx.x == 0) ? 0 : s[threadIdx.x - 1];
}

__global__ void k_scan_c(int* __restrict__ rowptr, const int* __restrict__ blocksums,
                         int N, int E) {
    int i = blockIdx.x * blockDim.x + threadIdx.x;
    if (i < N) rowptr[i] += blocksums[i >> 10];
    if (i == 0) rowptr[N] = E;
}

// per-bucket CSR placement: col writes confined to this bucket's rowptr range
__global__ __launch_bounds__(256) void k_place(const unsigned* __restrict__ pairs,
                                               const int* __restrict__ gcursor,
                                               const int* __restrict__ rowptr,
                                               int* __restrict__ col, int cap, int N) {
    __shared__ int lcur[256];
    const int b = blockIdx.x, tid = threadIdx.x;
    int row = b * 256 + tid;
    lcur[tid] = (row < N) ? rowptr[row] : 0;
    __syncthreads();
    const int cnt = min(gcursor[b], cap);
    const unsigned* p = pairs + (long long)b * cap;
    for (int i = tid; i < cnt; i += 256) {
        unsigned pk = p[i];
        int pos = atomicAdd(&lcur[pk & 255], 1);
        col[pos] = (int)(pk >> 8);
    }
}

// ---------------- register-blocked matmuls ----------------
// L1: H[N,64] = X[N,128] @ W[128,64]. 32 rows/block, 8 rows/wave, lane = col.
// sX reads are wave-uniform broadcasts; sW reads stride-1 -> conflict-free.

__global__ __launch_bounds__(256) void k_mm1(const float* __restrict__ X,
                                             const float* __restrict__ W,
                                             float* __restrict__ H, int N) {
    __shared__ float sW[128 * 64];  // 32 KB
    __shared__ float sX[32 * 128];  // 16 KB
    const int tid = threadIdx.x;
    for (int i = tid; i < 2048; i += 256) ((float4*)sW)[i] = ((const float4*)W)[i];
    const long long row0 = (long long)blockIdx.x * 32;
    for (int i = tid; i < 1024; i += 256) {
        long long r = row0 + (i >> 5);  // 32 float4 per row
        ((float4*)sX)[i] = (r < N) ? ((const float4*)(X + row0 * 128))[i]
                                   : make_float4(0.f, 0.f, 0.f, 0.f);
    }
    __syncthreads();
    const int wv = tid >> 6, lane = tid & 63;
    const int rbase = wv * 8;
    float acc[8] = {};
    for (int k = 0; k < 128; k += 4) {
        float4 xv[8];
#pragma unroll
        for (int r = 0; r < 8; ++r) xv[r] = *(const float4*)&sX[(rbase + r) * 128 + k];
        float w0 = sW[k * 64 + lane];
        float w1 = sW[(k + 1) * 64 + lane];
        float w2 = sW[(k + 2) * 64 + lane];
        float w3 = sW[(k + 3) * 64 + lane];
#pragma unroll
        for (int r = 0; r < 8; ++r)
            acc[r] += xv[r].x * w0 + xv[r].y * w1 + xv[r].z * w2 + xv[r].w * w3;
    }
#pragma unroll
    for (int r = 0; r < 8; ++r) {
        long long row = row0 + rbase + r;
        if (row < N) H[row * 64 + lane] = acc[r];
    }
}

// L2: H[N,32] = relu(Z[N,64]) @ W[64,32]. 64 rows/block, 16 rows/wave
// (half-wave handles 8 rows; both halves read same sW words -> 2-way broadcast, free).

__global__ __launch_bounds__(256) void k_mm2(const float* __restrict__ Z,
                                             const float* __restrict__ W,
                                             float* __restrict__ H, int N) {
    __shared__ float sW[64 * 32];  // 8 KB
    __shared__ float sX[64 * 64];  // 16 KB
    const int tid = threadIdx.x;
    for (int i = tid; i < 512; i += 256) ((float4*)sW)[i] = ((const float4*)W)[i];
    const long long row0 = (long long)blockIdx.x * 64;
    for (int i = tid; i < 1024; i += 256) {
        long long r = row0 + (i >> 4);  // 16 float4 per row
        float4 v = (r < N) ? ((const float4*)(Z + row0 * 64))[i] : make_float4(0.f, 0.f, 0.f, 0.f);
        v.x = fmaxf(v.x, 0.f); v.y = fmaxf(v.y, 0.f);
        v.z = fmaxf(v.z, 0.f); v.w = fmaxf(v.w, 0.f);
        ((float4*)sX)[i] = v;
    }
    __syncthreads();
    const int wv = tid >> 6, lane = tid & 63;
    const int c = lane & 31, hf = lane >> 5;
    const int rbase = wv * 16 + hf * 8;
    float acc[8] = {};
    for (int k = 0; k < 64; k += 4) {
        float4 xv[8];
#pragma unroll
        for (int r = 0; r < 8; ++r) xv[r] = *(const float4*)&sX[(rbase + r) * 64 + k];
        float w0 = sW[k * 32 + c];
        float w1 = sW[(k + 1) * 32 + c];
        float w2 = sW[(k + 2) * 32 + c];
        float w3 = sW[(k + 3) * 32 + c];
#pragma unroll
        for (int r = 0; r < 8; ++r)
            acc[r] += xv[r].x * w0 + xv[r].y * w1 + xv[r].z * w2 + xv[r].w * w3;
    }
#pragma unroll
    for (int r = 0; r < 8; ++r) {
        long long row = row0 + rbase + r;
        if (row < N) H[row * 32 + c] = acc[r];
    }
}

// ---------------- CSR aggregation (gather, no atomics) ----------------

__global__ __launch_bounds__(256) void k_agg64(const float* __restrict__ h,
                                               const int* __restrict__ rowptr,
                                               const int* __restrict__ col,
                                               const float* __restrict__ dis,
                                               const float* __restrict__ b,
                                               float* __restrict__ z, int N) {
    const int wave = (blockIdx.x * 256 + threadIdx.x) >> 6;
    const int lane = threadIdx.x & 63;
    if (wave >= N) return;
    const int row = wave;
    const float dr = dis[row];
    float acc = dr * h[(long long)row * 64 + lane];
    int j = rowptr[row];
    const int end = rowptr[row + 1];
    for (; j + 1 < end; j += 2) {
        int s0 = col[j], s1 = col[j + 1];
        float a0 = dis[s0] * h[(long long)s0 * 64 + lane];
        float a1 = dis[s1] * h[(long long)s1 * 64 + lane];
        acc += a0 + a1;
    }
    if (j < end) {
        int s0 = col[j];
        acc += dis[s0] * h[(long long)s0 * 64 + lane];
    }
    z[(long long)row * 64 + lane] = b[lane] + dr * acc;
}

__global__ __launch_bounds__(256) void k_agg32(const float* __restrict__ h,
                                               const int* __restrict__ rowptr,
                                               const int* __restrict__ col,
                                               const float* __restrict__ dis,
                                               const float* __restrict__ b,
                                               float* __restrict__ out, int N) {
    const int wave = (blockIdx.x * 256 + threadIdx.x) >> 6;
    const int lane = threadIdx.x & 63;
    if (wave >= N) return;
    const int row = wave;
    const int c = lane & 31;
    const int half = lane >> 5;
    const float dr = dis[row];
    float acc = half ? 0.0f : dr * h[(long long)row * 32 + c];
    const int start = rowptr[row], end = rowptr[row + 1];
    for (int j = start + half; j < end; j += 2) {
        int s = col[j];
        acc += dis[s] * h[(long long)s * 32 + c];
    }
    acc += __shfl_down(acc, 32);
    if (!half) out[(long long)row * 32 + c] = b[c] + dr * acc;
}

extern "C" void kernel_launch(void* const* d_in, const int* in_sizes, int n_in,
                              void* d_out, int out_size, void* d_ws, size_t ws_size,
                              hipStream_t stream) {
    const float* x  = (const float*)d_in[0];
    const int*   ei = (const int*)d_in[1];
    const float* W1 = (const float*)d_in[2];
    const float* b1 = (const float*)d_in[3];
    const float* W2 = (const float*)d_in[4];
    const float* b2 = (const float*)d_in[5];
    float* out = (float*)d_out;

    const int N = in_sizes[0] / IN_CH;
    const int E = in_sizes[1] / 2;
    const int* esrc = ei;
    const int* edst = ei + E;

    const int nbk = (N + 255) >> 8;               // 256-row buckets (<= MAXB)
    const int per_b = (E + nbk - 1) / nbk;
    const int cap = per_b + per_b / 4 + 256;      // ~20-sigma headroom

    // workspace layout (4-byte elems, regions padded to 16)
    int* counts    = (int*)d_ws;                        // N
    int* rowptr    = counts + ((N + 15) & ~15);         // N+1
    int* blocksums = rowptr + (((N + 1) + 15) & ~15);   // 256
    int* gcursor   = blocksums + 256;                   // MAXB
    int* col       = gcursor + MAXB;                    // E
    float* dis     = (float*)(col + ((E + 15) & ~15));  // N
    float* h1      = dis + ((N + 15) & ~15);            // N*64
    float* z1      = h1 + (long long)N * HID_CH;        // N*64
    unsigned* pairs = (unsigned*)z1;                    // nbk*cap <= N*64, dead before agg64
    float* h2      = h1;                                // h1 dead after agg64

    const int B = 256;
    const int nb = (N + 1023) / 1024;

    // ---- CSR build ----
    hipMemsetAsync(gcursor, 0, MAXB * sizeof(int), stream);
    k_partition<<<(E + EPB - 1) / EPB, B, 0, stream>>>(esrc, edst, gcursor, pairs, E, nbk, cap);
    k_bucket_counts<<<nbk, B, 0, stream>>>(pairs, gcursor, counts, dis, cap, N);
    k_scan_a<<<nb, B, 0, stream>>>(counts, rowptr, blocksums, N);
    k_scan_b<<<1, B, 0, stream>>>(blocksums, nb);
    k_scan_c<<<(N + B - 1) / B, B, 0, stream>>>(rowptr, blocksums, N, E);
    k_place<<<nbk, B, 0, stream>>>(pairs, gcursor, rowptr, col, cap, N);

    // ---- layer 1 ----
    k_mm1<<<(N + 31) / 32, B, 0, stream>>>(x, W1, h1, N);
    k_agg64<<<((long long)N * 64 + B - 1) / B, B, 0, stream>>>(h1, rowptr, col, dis, b1, z1, N);

    // ---- layer 2 ----
    k_mm2<<<(N + 63) / 64, B, 0, stream>>>(z1, W2, h2, N);
    k_agg32<<<((long long)N * 64 + B - 1) / B, B, 0, stream>>>(h2, rowptr, col, dis, b2, out, N);
}

// Round 4
// 351.013 us; speedup vs baseline: 2.3238x; 1.2477x over previous
//
#include <hip/hip_runtime.h>
#include <hip/hip_bf16.h>

#define IN_CH 128
#define HID_CH 64
#define OUT_CH 32
#define EPB 2048  // edges per partition block
#define MAXB 512  // max buckets (N <= 131072)

typedef unsigned short ushort_t;

static __device__ __forceinline__ ushort_t f2bf(float f) {
    unsigned u = __float_as_uint(f);
    unsigned r = (u + 0x7fff + ((u >> 16) & 1)) >> 16;  // RNE
    return (ushort_t)r;
}
static __device__ __forceinline__ float bf_lo(unsigned u) { return __uint_as_float(u << 16); }
static __device__ __forceinline__ float bf_hi(unsigned u) { return __uint_as_float(u & 0xffff0000u); }

// ---------------- single-pass radix partition by dst>>8 ----------------

__global__ __launch_bounds__(256) void k_partition(const int* __restrict__ src,
                                                   const int* __restrict__ dst,
                                                   int* __restrict__ gcursor,
                                                   unsigned* __restrict__ pairs,
                                                   int E, int nbk, int cap) {
    __shared__ int lhist[MAXB];
    __shared__ int lbase[MAXB];
    __shared__ int lcur[MAXB];
    const int tid = threadIdx.x;
    for (int b = tid; b < nbk; b += 256) { lhist[b] = 0; lcur[b] = 0; }
    __syncthreads();
    int s[8], d[8];
    const int e0 = blockIdx.x * EPB;
#pragma unroll
    for (int j = 0; j < 8; ++j) {
        int e = e0 + j * 256 + tid;
        if (e < E) {
            s[j] = src[e];
            d[j] = dst[e];
            atomicAdd(&lhist[d[j] >> 8], 1);
        } else {
            d[j] = -1;
        }
    }
    __syncthreads();
    for (int b = tid; b < nbk; b += 256)
        lbase[b] = lhist[b] ? atomicAdd(&gcursor[b], lhist[b]) : 0;
    __syncthreads();
#pragma unroll
    for (int j = 0; j < 8; ++j) {
        if (d[j] >= 0) {
            int b = d[j] >> 8;
            int loc = atomicAdd(&lcur[b], 1);
            int idx = lbase[b] + loc;
            if (idx < cap)
                pairs[(long long)b * cap + idx] = ((unsigned)s[j] << 8) | (unsigned)(d[j] & 255);
        }
    }
}

// exclusive scan over bucket totals (nbk <= 512); also writes rowptr[N] = grand total
__global__ __launch_bounds__(512) void k_bscan(const int* __restrict__ gcursor,
                                               int* __restrict__ bbase,
                                               int* __restrict__ rowptr,
                                               int nbk, int cap, int N) {
    __shared__ int s[512];
    const int tid = threadIdx.x;
    int v = (tid < nbk) ? min(gcursor[tid], cap) : 0;
    s[tid] = v;
    __syncthreads();
    for (int off = 1; off < 512; off <<= 1) {
        int val = (tid >= off) ? s[tid - off] : 0;
        __syncthreads();
        s[tid] += val;
        __syncthreads();
    }
    if (tid < nbk) bbase[tid] = s[tid] - v;
    if (tid == nbk - 1) rowptr[N] = s[tid];
}

// fused per-bucket: row counts -> LDS scan -> rowptr + dis -> direct col placement
__global__ __launch_bounds__(256) void k_bucket_build(const unsigned* __restrict__ pairs,
                                                      const int* __restrict__ gcursor,
                                                      const int* __restrict__ bbase,
                                                      int* __restrict__ rowptr,
                                                      int* __restrict__ col,
                                                      float* __restrict__ dis,
                                                      int cap, int N) {
    __shared__ int lc[256];
    __shared__ int ls[256];
    __shared__ int lcur[256];
    const int b = blockIdx.x, tid = threadIdx.x;
    lc[tid] = 0;
    __syncthreads();
    const int cnt = min(gcursor[b], cap);
    const int base = bbase[b];
    const unsigned* p = pairs + (long long)b * cap;
    for (int i = tid; i < cnt; i += 256) atomicAdd(&lc[p[i] & 255], 1);
    __syncthreads();
    const int v = lc[tid];
    ls[tid] = v;
    __syncthreads();
    for (int off = 1; off < 256; off <<= 1) {
        int val = (tid >= off) ? ls[tid - off] : 0;
        __syncthreads();
        ls[tid] += val;
        __syncthreads();
    }
    const int excl = ls[tid] - v;
    const int row = b * 256 + tid;
    if (row < N) {
        rowptr[row] = base + excl;
        dis[row] = rsqrtf((float)(v + 1));  // +1 self-loop
    }
    lcur[tid] = base + excl;
    __syncthreads();
    for (int i = tid; i < cnt; i += 256) {
        unsigned pk = p[i];
        int pos = atomicAdd(&lcur[pk & 255], 1);
        col[pos] = (int)(pk >> 8);
    }
}

// ---------------- register-blocked matmuls ----------------
// L1: H[N,64] = X[N,128] @ W[128,64], output stored bf16.

__global__ __launch_bounds__(256) void k_mm1(const float* __restrict__ X,
                                             const float* __restrict__ W,
                                             ushort_t* __restrict__ H, int N) {
    __shared__ float sW[128 * 64];  // 32 KB
    __shared__ float sX[32 * 128];  // 16 KB
    const int tid = threadIdx.x;
    for (int i = tid; i < 2048; i += 256) ((float4*)sW)[i] = ((const float4*)W)[i];
    const long long row0 = (long long)blockIdx.x * 32;
    for (int i = tid; i < 1024; i += 256) {
        long long r = row0 + (i >> 5);
        ((float4*)sX)[i] = (r < N) ? ((const float4*)(X + row0 * 128))[i]
                                   : make_float4(0.f, 0.f, 0.f, 0.f);
    }
    __syncthreads();
    const int wv = tid >> 6, lane = tid & 63;
    const int rbase = wv * 8;
    float acc[8] = {};
    for (int k = 0; k < 128; k += 4) {
        float4 xv[8];
#pragma unroll
        for (int r = 0; r < 8; ++r) xv[r] = *(const float4*)&sX[(rbase + r) * 128 + k];
        float w0 = sW[k * 64 + lane];
        float w1 = sW[(k + 1) * 64 + lane];
        float w2 = sW[(k + 2) * 64 + lane];
        float w3 = sW[(k + 3) * 64 + lane];
#pragma unroll
        for (int r = 0; r < 8; ++r)
            acc[r] += xv[r].x * w0 + xv[r].y * w1 + xv[r].z * w2 + xv[r].w * w3;
    }
#pragma unroll
    for (int r = 0; r < 8; ++r) {
        long long row = row0 + rbase + r;
        if (row < N) H[row * 64 + lane] = f2bf(acc[r]);
    }
}

// L2: H[N,32] = relu(Z[N,64]) @ W[64,32], output stored bf16.

__global__ __launch_bounds__(256) void k_mm2(const float* __restrict__ Z,
                                             const float* __restrict__ W,
                                             ushort_t* __restrict__ H, int N) {
    __shared__ float sW[64 * 32];  // 8 KB
    __shared__ float sX[64 * 64];  // 16 KB
    const int tid = threadIdx.x;
    for (int i = tid; i < 512; i += 256) ((float4*)sW)[i] = ((const float4*)W)[i];
    const long long row0 = (long long)blockIdx.x * 64;
    for (int i = tid; i < 1024; i += 256) {
        long long r = row0 + (i >> 4);
        float4 v = (r < N) ? ((const float4*)(Z + row0 * 64))[i] : make_float4(0.f, 0.f, 0.f, 0.f);
        v.x = fmaxf(v.x, 0.f); v.y = fmaxf(v.y, 0.f);
        v.z = fmaxf(v.z, 0.f); v.w = fmaxf(v.w, 0.f);
        ((float4*)sX)[i] = v;
    }
    __syncthreads();
    const int wv = tid >> 6, lane = tid & 63;
    const int c = lane & 31, hf = lane >> 5;
    const int rbase = wv * 16 + hf * 8;
    float acc[8] = {};
    for (int k = 0; k < 64; k += 4) {
        float4 xv[8];
#pragma unroll
        for (int r = 0; r < 8; ++r) xv[r] = *(const float4*)&sX[(rbase + r) * 64 + k];
        float w0 = sW[k * 32 + c];
        float w1 = sW[(k + 1) * 32 + c];
        float w2 = sW[(k + 2) * 32 + c];
        float w3 = sW[(k + 3) * 32 + c];
#pragma unroll
        for (int r = 0; r < 8; ++r)
            acc[r] += xv[r].x * w0 + xv[r].y * w1 + xv[r].z * w2 + xv[r].w * w3;
    }
#pragma unroll
    for (int r = 0; r < 8; ++r) {
        long long row = row0 + rbase + r;
        if (row < N) H[row * 32 + c] = f2bf(acc[r]);
    }
}

// ---------------- CSR aggregation: bf16 gather, fp32 accumulate ----------------
// agg64: wave per dst row; half-wave per edge; lane handles channel pair (2t,2t+1).

__global__ __launch_bounds__(256) void k_agg64(const unsigned* __restrict__ h,
                                               const int* __restrict__ rowptr,
                                               const int* __restrict__ col,
                                               const float* __restrict__ dis,
                                               const float* __restrict__ b,
                                               float* __restrict__ z, int N) {
    const int wave = (blockIdx.x * 256 + threadIdx.x) >> 6;
    const int lane = threadIdx.x & 63;
    if (wave >= N) return;
    const int row = wave;
    const int t = lane & 31, hf = lane >> 5;
    const float dr = dis[row];
    float ax = 0.f, ay = 0.f;
    if (!hf) {
        unsigned u = h[row * 32 + t];  // self-loop
        ax = dr * bf_lo(u);
        ay = dr * bf_hi(u);
    }
    int j = rowptr[row] + hf;
    const int end = rowptr[row + 1];
    for (; j + 2 < end; j += 4) {
        int s0 = col[j], s1 = col[j + 2];
        float w0 = dis[s0], w1 = dis[s1];
        unsigned u0 = h[s0 * 32 + t], u1 = h[s1 * 32 + t];
        ax += w0 * bf_lo(u0) + w1 * bf_lo(u1);
        ay += w0 * bf_hi(u0) + w1 * bf_hi(u1);
    }
    if (j < end) {
        int s0 = col[j];
        float w0 = dis[s0];
        unsigned u0 = h[s0 * 32 + t];
        ax += w0 * bf_lo(u0);
        ay += w0 * bf_hi(u0);
    }
    ax += __shfl_down(ax, 32);
    ay += __shfl_down(ay, 32);
    if (!hf) {
        float2 bv = ((const float2*)b)[t];
        float2 o;
        o.x = bv.x + dr * ax;
        o.y = bv.y + dr * ay;
        ((float2*)z)[row * 32 + t] = o;
    }
}

// agg32: wave per dst row; quarter-wave per edge; lane handles channel pair.

__global__ __launch_bounds__(256) void k_agg32(const unsigned* __restrict__ h,
                                               const int* __restrict__ rowptr,
                                               const int* __restrict__ col,
                                               const float* __restrict__ dis,
                                               const float* __restrict__ b,
                                               float* __restrict__ out, int N) {
    const int wave = (blockIdx.x * 256 + threadIdx.x) >> 6;
    const int lane = threadIdx.x & 63;
    if (wave >= N) return;
    const int row = wave;
    const int t = lane & 15, q = lane >> 4;
    const float dr = dis[row];
    float ax = 0.f, ay = 0.f;
    if (q == 0) {
        unsigned u = h[row * 16 + t];  // self-loop
        ax = dr * bf_lo(u);
        ay = dr * bf_hi(u);
    }
    int j = rowptr[row] + q;
    const int end = rowptr[row + 1];
    for (; j + 4 < end; j += 8) {
        int s0 = col[j], s1 = col[j + 4];
        float w0 = dis[s0], w1 = dis[s1];
        unsigned u0 = h[s0 * 16 + t], u1 = h[s1 * 16 + t];
        ax += w0 * bf_lo(u0) + w1 * bf_lo(u1);
        ay += w0 * bf_hi(u0) + w1 * bf_hi(u1);
    }
    if (j < end) {
        int s0 = col[j];
        float w0 = dis[s0];
        unsigned u0 = h[s0 * 16 + t];
        ax += w0 * bf_lo(u0);
        ay += w0 * bf_hi(u0);
    }
    ax += __shfl_down(ax, 32);
    ay += __shfl_down(ay, 32);
    ax += __shfl_down(ax, 16);
    ay += __shfl_down(ay, 16);
    if (q == 0) {
        float2 bv = ((const float2*)b)[t];
        float2 o;
        o.x = bv.x + dr * ax;
        o.y = bv.y + dr * ay;
        ((float2*)out)[row * 16 + t] = o;
    }
}

extern "C" void kernel_launch(void* const* d_in, const int* in_sizes, int n_in,
                              void* d_out, int out_size, void* d_ws, size_t ws_size,
                              hipStream_t stream) {
    const float* x  = (const float*)d_in[0];
    const int*   ei = (const int*)d_in[1];
    const float* W1 = (const float*)d_in[2];
    const float* b1 = (const float*)d_in[3];
    const float* W2 = (const float*)d_in[4];
    const float* b2 = (const float*)d_in[5];
    float* out = (float*)d_out;

    const int N = in_sizes[0] / IN_CH;
    const int E = in_sizes[1] / 2;
    const int* esrc = ei;
    const int* edst = ei + E;

    int nbk = (N + 255) >> 8;
    if (nbk > MAXB) nbk = MAXB;  // N <= 131072 by construction
    const int per_b = (E + nbk - 1) / nbk;
    const int cap = per_b + per_b / 4 + 256;  // ~20-sigma headroom

    // workspace layout (4-byte units, regions padded to 16)
    int* rowptr   = (int*)d_ws;                          // N+1
    int* gcursor  = rowptr + (((N + 1) + 15) & ~15);     // MAXB
    int* bbase    = gcursor + MAXB;                      // MAXB
    int* col      = bbase + MAXB;                        // E
    float* dis    = (float*)(col + ((E + 15) & ~15));    // N
    ushort_t* h1  = (ushort_t*)(dis + ((N + 15) & ~15)); // N*64 bf16
    float* z1     = (float*)(h1 + (((long long)N * 64 + 31) & ~31LL)); // N*64 f32
    unsigned* pairs = (unsigned*)z1;  // nbk*cap dwords (~8.4MB) <= N*64 floats, dead before agg64
    ushort_t* h2  = h1;               // h1 dead after agg64

    const int B = 256;

    hipMemsetAsync(gcursor, 0, MAXB * sizeof(int), stream);
    k_partition<<<(E + EPB - 1) / EPB, B, 0, stream>>>(esrc, edst, gcursor, pairs, E, nbk, cap);
    k_bscan<<<1, 512, 0, stream>>>(gcursor, bbase, rowptr, nbk, cap, N);
    k_bucket_build<<<nbk, B, 0, stream>>>(pairs, gcursor, bbase, rowptr, col, dis, cap, N);

    k_mm1<<<(N + 31) / 32, B, 0, stream>>>(x, W1, h1, N);
    k_agg64<<<((long long)N * 64 + B - 1) / B, B, 0, stream>>>((const unsigned*)h1, rowptr, col, dis, b1, z1, N);

    k_mm2<<<(N + 63) / 64, B, 0, stream>>>(z1, W2, h2, N);
    k_agg32<<<((long long)N * 64 + B - 1) / B, B, 0, stream>>>((const unsigned*)h2, rowptr, col, dis, b2, out, N);
}

// Round 5
// 293.497 us; speedup vs baseline: 2.7792x; 1.1960x over previous
//
#include <hip/hip_runtime.h>
#include <hip/hip_bf16.h>

#define IN_CH 128
#define HID_CH 64
#define OUT_CH 32
#define EPB 2048  // edges per partition block
#define MAXB 512  // max buckets (N <= 131072)

typedef unsigned short ushort_t;

static __device__ __forceinline__ ushort_t f2bf(float f) {
    unsigned u = __float_as_uint(f);
    unsigned r = (u + 0x7fff + ((u >> 16) & 1)) >> 16;  // RNE
    return (ushort_t)r;
}
static __device__ __forceinline__ float bf_lo(unsigned u) { return __uint_as_float(u << 16); }
static __device__ __forceinline__ float bf_hi(unsigned u) { return __uint_as_float(u & 0xffff0000u); }

// ---------------- single-pass radix partition by dst>>8 ----------------

__global__ __launch_bounds__(256) void k_partition(const int* __restrict__ src,
                                                   const int* __restrict__ dst,
                                                   int* __restrict__ gcursor,
                                                   unsigned* __restrict__ pairs,
                                                   int E, int nbk, int cap) {
    __shared__ int lhist[MAXB];
    __shared__ int lbase[MAXB];
    __shared__ int lcur[MAXB];
    const int tid = threadIdx.x;
    for (int b = tid; b < nbk; b += 256) { lhist[b] = 0; lcur[b] = 0; }
    __syncthreads();
    int s[8], d[8];
    const int e0 = blockIdx.x * EPB;
#pragma unroll
    for (int j = 0; j < 8; ++j) {
        int e = e0 + j * 256 + tid;
        if (e < E) {
            s[j] = src[e];
            d[j] = dst[e];
            atomicAdd(&lhist[d[j] >> 8], 1);
        } else {
            d[j] = -1;
        }
    }
    __syncthreads();
    for (int b = tid; b < nbk; b += 256)
        lbase[b] = lhist[b] ? atomicAdd(&gcursor[b], lhist[b]) : 0;
    __syncthreads();
#pragma unroll
    for (int j = 0; j < 8; ++j) {
        if (d[j] >= 0) {
            int b = d[j] >> 8;
            int loc = atomicAdd(&lcur[b], 1);
            int idx = lbase[b] + loc;
            if (idx < cap)
                pairs[(long long)b * cap + idx] = ((unsigned)s[j] << 8) | (unsigned)(d[j] & 255);
        }
    }
}

// exclusive scan over bucket totals (nbk <= 512); also writes rowptr[N] = grand total
__global__ __launch_bounds__(512) void k_bscan(const int* __restrict__ gcursor,
                                               int* __restrict__ bbase,
                                               int* __restrict__ rowptr,
                                               int nbk, int cap, int N) {
    __shared__ int s[512];
    const int tid = threadIdx.x;
    int v = (tid < nbk) ? min(gcursor[tid], cap) : 0;
    s[tid] = v;
    __syncthreads();
    for (int off = 1; off < 512; off <<= 1) {
        int val = (tid >= off) ? s[tid - off] : 0;
        __syncthreads();
        s[tid] += val;
        __syncthreads();
    }
    if (tid < nbk) bbase[tid] = s[tid] - v;
    if (tid == nbk - 1) rowptr[N] = s[tid];
}

// fused per-bucket: row counts -> LDS scan -> rowptr + dis -> direct col placement
__global__ __launch_bounds__(256) void k_bucket_build(const unsigned* __restrict__ pairs,
                                                      const int* __restrict__ gcursor,
                                                      const int* __restrict__ bbase,
                                                      int* __restrict__ rowptr,
                                                      int* __restrict__ col,
                                                      float* __restrict__ dis,
                                                      int cap, int N) {
    __shared__ int lc[256];
    __shared__ int ls[256];
    __shared__ int lcur[256];
    const int b = blockIdx.x, tid = threadIdx.x;
    lc[tid] = 0;
    __syncthreads();
    const int cnt = min(gcursor[b], cap);
    const int base = bbase[b];
    const unsigned* p = pairs + (long long)b * cap;
    for (int i = tid; i < cnt; i += 256) atomicAdd(&lc[p[i] & 255], 1);
    __syncthreads();
    const int v = lc[tid];
    ls[tid] = v;
    __syncthreads();
    for (int off = 1; off < 256; off <<= 1) {
        int val = (tid >= off) ? ls[tid - off] : 0;
        __syncthreads();
        ls[tid] += val;
        __syncthreads();
    }
    const int excl = ls[tid] - v;
    const int row = b * 256 + tid;
    if (row < N) {
        rowptr[row] = base + excl;
        dis[row] = rsqrtf((float)(v + 1));  // +1 self-loop
    }
    lcur[tid] = base + excl;
    __syncthreads();
    for (int i = tid; i < cnt; i += 256) {
        unsigned pk = p[i];
        int pos = atomicAdd(&lcur[pk & 255], 1);
        col[pos] = (int)(pk >> 8);
    }
}

// ---------------- register-blocked matmuls ----------------
// L1: H[N,64] = X[N,128] @ W[128,64], output stored bf16.

__global__ __launch_bounds__(256) void k_mm1(const float* __restrict__ X,
                                             const float* __restrict__ W,
                                             ushort_t* __restrict__ H, int N) {
    __shared__ float sW[128 * 64];  // 32 KB
    __shared__ float sX[32 * 128];  // 16 KB
    const int tid = threadIdx.x;
    for (int i = tid; i < 2048; i += 256) ((float4*)sW)[i] = ((const float4*)W)[i];
    const long long row0 = (long long)blockIdx.x * 32;
    for (int i = tid; i < 1024; i += 256) {
        long long r = row0 + (i >> 5);
        ((float4*)sX)[i] = (r < N) ? ((const float4*)(X + row0 * 128))[i]
                                   : make_float4(0.f, 0.f, 0.f, 0.f);
    }
    __syncthreads();
    const int wv = tid >> 6, lane = tid & 63;
    const int rbase = wv * 8;
    float acc[8] = {};
    for (int k = 0; k < 128; k += 4) {
        float4 xv[8];
#pragma unroll
        for (int r = 0; r < 8; ++r) xv[r] = *(const float4*)&sX[(rbase + r) * 128 + k];
        float w0 = sW[k * 64 + lane];
        float w1 = sW[(k + 1) * 64 + lane];
        float w2 = sW[(k + 2) * 64 + lane];
        float w3 = sW[(k + 3) * 64 + lane];
#pragma unroll
        for (int r = 0; r < 8; ++r)
            acc[r] += xv[r].x * w0 + xv[r].y * w1 + xv[r].z * w2 + xv[r].w * w3;
    }
#pragma unroll
    for (int r = 0; r < 8; ++r) {
        long long row = row0 + rbase + r;
        if (row < N) H[row * 64 + lane] = f2bf(acc[r]);
    }
}

// L2: H[N,32] = relu(Z[N,64]) @ W[64,32]; Z is packed bf16x2 (32 dwords/row); out bf16.

__global__ __launch_bounds__(256) void k_mm2(const unsigned* __restrict__ Z,
                                             const float* __restrict__ W,
                                             ushort_t* __restrict__ H, int N) {
    __shared__ float sW[64 * 32];  // 8 KB
    __shared__ float sX[64 * 64];  // 16 KB
    const int tid = threadIdx.x;
    for (int i = tid; i < 512; i += 256) ((float4*)sW)[i] = ((const float4*)W)[i];
    const long long row0 = (long long)blockIdx.x * 64;
    for (int i = tid; i < 2048; i += 256) {
        int r = i >> 5;         // local row
        int cp = i & 31;        // channel pair
        long long row = row0 + r;
        unsigned u = (row < N) ? Z[row * 32 + cp] : 0u;
        sX[r * 64 + 2 * cp]     = fmaxf(bf_lo(u), 0.f);
        sX[r * 64 + 2 * cp + 1] = fmaxf(bf_hi(u), 0.f);
    }
    __syncthreads();
    const int wv = tid >> 6, lane = tid & 63;
    const int c = lane & 31, hf = lane >> 5;
    const int rbase = wv * 16 + hf * 8;
    float acc[8] = {};
#pragma unroll 2
    for (int k = 0; k < 64; k += 4) {
        float4 xv[8];
#pragma unroll
        for (int r = 0; r < 8; ++r) xv[r] = *(const float4*)&sX[(rbase + r) * 64 + k];
        float w0 = sW[k * 32 + c];
        float w1 = sW[(k + 1) * 32 + c];
        float w2 = sW[(k + 2) * 32 + c];
        float w3 = sW[(k + 3) * 32 + c];
#pragma unroll
        for (int r = 0; r < 8; ++r)
            acc[r] += xv[r].x * w0 + xv[r].y * w1 + xv[r].z * w2 + xv[r].w * w3;
    }
#pragma unroll
    for (int r = 0; r < 8; ++r) {
        long long row = row0 + rbase + r;
        if (row < N) H[row * 32 + c] = f2bf(acc[r]);
    }
}

// ---------------- CSR aggregation: bf16 gather, fp32 accumulate ----------------
// Wave per dst row. Preload up to 64 (col,dis) into registers (one coalesced load),
// broadcast via shfl -> gather addresses have no global-load dependency.

// agg64: 32 lanes per edge (channel pairs), 2 edge groups.
__global__ __launch_bounds__(256) void k_agg64(const unsigned* __restrict__ h,
                                               const int* __restrict__ rowptr,
                                               const int* __restrict__ col,
                                               const float* __restrict__ dis,
                                               const float* __restrict__ b,
                                               unsigned* __restrict__ z, int N) {
    const int wave = (blockIdx.x * 256 + threadIdx.x) >> 6;
    const int lane = threadIdx.x & 63;
    if (wave >= N) return;
    const int row = wave;
    const int t = lane & 31, g = lane >> 5;
    const int start = rowptr[row];
    const int deg = rowptr[row + 1] - start;
    const float dr = dis[row];

    int myCol = row;
    float myDis = 0.f;
    if (lane < deg) {
        myCol = col[start + lane];
        myDis = dis[myCol];
    }

    unsigned us = h[row * 32 + t];  // self-loop (counted once via g==0)
    float w0s = g ? 0.f : dr;
    float ax = w0s * bf_lo(us), ay = w0s * bf_hi(us);

    const int cnt = min(deg, 64);
    for (int k0 = 0; k0 < cnt; k0 += 8) {
#pragma unroll
        for (int u = 0; u < 4; ++u) {
            int slot = k0 + 2 * u + g;
            int s = __shfl(myCol, slot);
            float w = __shfl(myDis, slot);
            unsigned uu = h[s * 32 + t];
            ax += w * bf_lo(uu);
            ay += w * bf_hi(uu);
        }
    }
    // rare tail: deg > 64
    for (int j = start + 64 + g; j < start + deg; j += 2) {
        int s = col[j];
        float w = dis[s];
        unsigned uu = h[s * 32 + t];
        ax += w * bf_lo(uu);
        ay += w * bf_hi(uu);
    }
    ax += __shfl_down(ax, 32);
    ay += __shfl_down(ay, 32);
    if (!g) {
        float2 bv = ((const float2*)b)[t];
        float ox = bv.x + dr * ax;
        float oy = bv.y + dr * ay;
        z[row * 32 + t] = (unsigned)f2bf(ox) | ((unsigned)f2bf(oy) << 16);
    }
}

// agg32: 16 lanes per edge (channel pairs), 4 edge groups; fp32 output (final).
__global__ __launch_bounds__(256) void k_agg32(const unsigned* __restrict__ h,
                                               const int* __restrict__ rowptr,
                                               const int* __restrict__ col,
                                               const float* __restrict__ dis,
                                               const float* __restrict__ b,
                                               float* __restrict__ out, int N) {
    const int wave = (blockIdx.x * 256 + threadIdx.x) >> 6;
    const int lane = threadIdx.x & 63;
    if (wave >= N) return;
    const int row = wave;
    const int t = lane & 15, g = lane >> 4;
    const int start = rowptr[row];
    const int deg = rowptr[row + 1] - start;
    const float dr = dis[row];

    int myCol = row;
    float myDis = 0.f;
    if (lane < deg) {
        myCol = col[start + lane];
        myDis = dis[myCol];
    }

    unsigned us = h[row * 16 + t];
    float w0s = g ? 0.f : dr;
    float ax = w0s * bf_lo(us), ay = w0s * bf_hi(us);

    const int cnt = min(deg, 64);
    for (int k0 = 0; k0 < cnt; k0 += 16) {
#pragma unroll
        for (int u = 0; u < 4; ++u) {
            int slot = k0 + 4 * u + g;
            int s = __shfl(myCol, slot);
            float w = __shfl(myDis, slot);
            unsigned uu = h[s * 16 + t];
            ax += w * bf_lo(uu);
            ay += w * bf_hi(uu);
        }
    }
    for (int j = start + 64 + g; j < start + deg; j += 4) {
        int s = col[j];
        float w = dis[s];
        unsigned uu = h[s * 16 + t];
        ax += w * bf_lo(uu);
        ay += w * bf_hi(uu);
    }
    ax += __shfl_down(ax, 32);
    ay += __shfl_down(ay, 32);
    ax += __shfl_down(ax, 16);
    ay += __shfl_down(ay, 16);
    if (!g) {
        float2 bv = ((const float2*)b)[t];
        float2 o;
        o.x = bv.x + dr * ax;
        o.y = bv.y + dr * ay;
        ((float2*)out)[row * 16 + t] = o;
    }
}

extern "C" void kernel_launch(void* const* d_in, const int* in_sizes, int n_in,
                              void* d_out, int out_size, void* d_ws, size_t ws_size,
                              hipStream_t stream) {
    const float* x  = (const float*)d_in[0];
    const int*   ei = (const int*)d_in[1];
    const float* W1 = (const float*)d_in[2];
    const float* b1 = (const float*)d_in[3];
    const float* W2 = (const float*)d_in[4];
    const float* b2 = (const float*)d_in[5];
    float* out = (float*)d_out;

    const int N = in_sizes[0] / IN_CH;
    const int E = in_sizes[1] / 2;
    const int* esrc = ei;
    const int* edst = ei + E;

    int nbk = (N + 255) >> 8;
    if (nbk > MAXB) nbk = MAXB;
    const int per_b = (E + nbk - 1) / nbk;
    const int cap = per_b + per_b / 4 + 256;  // ~20-sigma headroom

    // workspace layout (4-byte units, regions padded to 16)
    int* rowptr   = (int*)d_ws;                          // N+1
    int* gcursor  = rowptr + (((N + 1) + 15) & ~15);     // MAXB
    int* bbase    = gcursor + MAXB;                      // MAXB
    int* col      = bbase + MAXB;                        // E
    float* dis    = (float*)(col + ((E + 15) & ~15));    // N
    ushort_t* h1  = (ushort_t*)(dis + ((N + 15) & ~15)); // N*64 bf16
    unsigned* z1  = (unsigned*)(h1 + (((long long)N * 64 + 31) & ~31LL)); // N*32 dwords (bf16x2)
    unsigned* pairs = z1;             // nbk*cap dwords (~8.4MB) <= N*32 dwords (12.8MB), dead before agg64
    ushort_t* h2  = h1;               // h1 dead after agg64

    const int B = 256;

    hipMemsetAsync(gcursor, 0, MAXB * sizeof(int), stream);
    k_partition<<<(E + EPB - 1) / EPB, B, 0, stream>>>(esrc, edst, gcursor, pairs, E, nbk, cap);
    k_bscan<<<1, 512, 0, stream>>>(gcursor, bbase, rowptr, nbk, cap, N);
    k_bucket_build<<<nbk, B, 0, stream>>>(pairs, gcursor, bbase, rowptr, col, dis, cap, N);

    k_mm1<<<(N + 31) / 32, B, 0, stream>>>(x, W1, h1, N);
    k_agg64<<<((long long)N * 64 + B - 1) / B, B, 0, stream>>>((const unsigned*)h1, rowptr, col, dis, b1, z1, N);

    k_mm2<<<(N + 63) / 64, B, 0, stream>>>(z1, W2, h2, N);
    k_agg32<<<((long long)N * 64 + B - 1) / B, B, 0, stream>>>((const unsigned*)h2, rowptr, col, dis, b2, out, N);
}

// Round 6
// 261.523 us; speedup vs baseline: 3.1189x; 1.1223x over previous
//
#include <hip/hip_runtime.h>
#include <hip/hip_bf16.h>

#define IN_CH 128
#define HID_CH 64
#define OUT_CH 32
#define EPB 2048  // edges per partition block
#define MAXB 512  // max buckets (N <= 131072)

typedef unsigned short ushort_t;
typedef __attribute__((ext_vector_type(8))) short short8;
typedef __attribute__((ext_vector_type(4))) float float4v;

static __device__ __forceinline__ ushort_t f2bf(float f) {
    unsigned u = __float_as_uint(f);
    unsigned r = (u + 0x7fff + ((u >> 16) & 1)) >> 16;  // RNE
    return (ushort_t)r;
}
static __device__ __forceinline__ float bf_lo(unsigned u) { return __uint_as_float(u << 16); }
static __device__ __forceinline__ float bf_hi(unsigned u) { return __uint_as_float(u & 0xffff0000u); }

// ---------------- single-pass radix partition by dst>>8 ----------------

__global__ __launch_bounds__(256) void k_partition(const int* __restrict__ src,
                                                   const int* __restrict__ dst,
                                                   int* __restrict__ gcursor,
                                                   unsigned* __restrict__ pairs,
                                                   int E, int nbk, int cap) {
    __shared__ int lhist[MAXB];
    __shared__ int lbase[MAXB];
    __shared__ int lcur[MAXB];
    const int tid = threadIdx.x;
    for (int b = tid; b < nbk; b += 256) { lhist[b] = 0; lcur[b] = 0; }
    __syncthreads();
    int s[8], d[8];
    const int e0 = blockIdx.x * EPB;
#pragma unroll
    for (int j = 0; j < 8; ++j) {
        int e = e0 + j * 256 + tid;
        if (e < E) {
            s[j] = src[e];
            d[j] = dst[e];
            atomicAdd(&lhist[d[j] >> 8], 1);
        } else {
            d[j] = -1;
        }
    }
    __syncthreads();
    for (int b = tid; b < nbk; b += 256)
        lbase[b] = lhist[b] ? atomicAdd(&gcursor[b], lhist[b]) : 0;
    __syncthreads();
#pragma unroll
    for (int j = 0; j < 8; ++j) {
        if (d[j] >= 0) {
            int b = d[j] >> 8;
            int loc = atomicAdd(&lcur[b], 1);
            int idx = lbase[b] + loc;
            if (idx < cap)
                pairs[(long long)b * cap + idx] = ((unsigned)s[j] << 8) | (unsigned)(d[j] & 255);
        }
    }
}

// exclusive scan over bucket totals (nbk <= 512); also writes rowptr[N] = grand total
__global__ __launch_bounds__(512) void k_bscan(const int* __restrict__ gcursor,
                                               int* __restrict__ bbase,
                                               int* __restrict__ rowptr,
                                               int nbk, int cap, int N) {
    __shared__ int s[512];
    const int tid = threadIdx.x;
    int v = (tid < nbk) ? min(gcursor[tid], cap) : 0;
    s[tid] = v;
    __syncthreads();
    for (int off = 1; off < 512; off <<= 1) {
        int val = (tid >= off) ? s[tid - off] : 0;
        __syncthreads();
        s[tid] += val;
        __syncthreads();
    }
    if (tid < nbk) bbase[tid] = s[tid] - v;
    if (tid == nbk - 1) rowptr[N] = s[tid];
}

// fused per-bucket: row counts -> LDS scan -> rowptr + dis -> direct col placement
__global__ __launch_bounds__(256) void k_bucket_build(const unsigned* __restrict__ pairs,
                                                      const int* __restrict__ gcursor,
                                                      const int* __restrict__ bbase,
                                                      int* __restrict__ rowptr,
                                                      int* __restrict__ col,
                                                      float* __restrict__ dis,
                                                      int cap, int N) {
    __shared__ int lc[256];
    __shared__ int ls[256];
    __shared__ int lcur[256];
    const int b = blockIdx.x, tid = threadIdx.x;
    lc[tid] = 0;
    __syncthreads();
    const int cnt = min(gcursor[b], cap);
    const int base = bbase[b];
    const unsigned* p = pairs + (long long)b * cap;
    for (int i = tid; i < cnt; i += 256) atomicAdd(&lc[p[i] & 255], 1);
    __syncthreads();
    const int v = lc[tid];
    ls[tid] = v;
    __syncthreads();
    for (int off = 1; off < 256; off <<= 1) {
        int val = (tid >= off) ? ls[tid - off] : 0;
        __syncthreads();
        ls[tid] += val;
        __syncthreads();
    }
    const int excl = ls[tid] - v;
    const int row = b * 256 + tid;
    if (row < N) {
        rowptr[row] = base + excl;
        dis[row] = rsqrtf((float)(v + 1));  // +1 self-loop
    }
    lcur[tid] = base + excl;
    __syncthreads();
    for (int i = tid; i < cnt; i += 256) {
        unsigned pk = p[i];
        int pos = atomicAdd(&lcur[pk & 255], 1);
        col[pos] = (int)(pk >> 8);
    }
}

// ---------------- W1 -> b-fragment repack (bf16) ----------------
// slot s = (kc*4+nt)*64 + lane; dword d of slot = bf16(W[k0+2d][c]) | bf16(W[k0+2d+1][c])<<16
// where k0 = kc*32 + (lane>>4)*8, c = nt*16 + (lane&15).

__global__ __launch_bounds__(256) void k_prepW(const float* __restrict__ W,
                                               unsigned* __restrict__ wsW) {
    int s = blockIdx.x * 256 + threadIdx.x;
    if (s >= 1024) return;
    int lane = s & 63;
    int nt = (s >> 6) & 3;
    int kc = s >> 8;
    int c = nt * 16 + (lane & 15);
    int k0 = kc * 32 + (lane >> 4) * 8;
    unsigned o[4];
#pragma unroll
    for (int d = 0; d < 4; ++d) {
        unsigned lo = f2bf(W[(k0 + 2 * d) * 64 + c]);
        unsigned hi = f2bf(W[(k0 + 2 * d + 1) * 64 + c]);
        o[d] = lo | (hi << 16);
    }
    ((uint4*)wsW)[s] = make_uint4(o[0], o[1], o[2], o[3]);
}

// ---------------- L1 matmul via MFMA: H[N,64] = bf16(X[N,128]) @ bf16(W1) ----------------
// 4 waves/block, wave = 16-row strip; no LDS, no barriers. a-frag from global fp32
// (cvt+pack), b-frags from prepacked wsW (L1-hot). acc fp32, output bf16.

__global__ __launch_bounds__(256) void k_mm1(const float* __restrict__ X,
                                             const unsigned* __restrict__ wsW,
                                             ushort_t* __restrict__ H, int N) {
    const int tid = threadIdx.x;
    const int wv = tid >> 6, lane = tid & 63;
    const int quad = lane >> 4, n16 = lane & 15;
    const int rowbase = blockIdx.x * 64 + wv * 16;  // this wave's 16-row strip
    const int myrow = rowbase + n16;                // row this lane's a-frag serves
    const bool rok = (myrow < N);

    float4v acc0 = {}, acc1 = {}, acc2 = {}, acc3 = {};

#pragma unroll
    for (int kc = 0; kc < 4; ++kc) {
        // a-frag: A[m=n16][k = kc*32 + quad*8 + j], j=0..7 (8 fp32 -> 8 bf16)
        float4 xa = make_float4(0.f, 0.f, 0.f, 0.f), xb = xa;
        if (rok) {
            const float4* p = (const float4*)(X + (long long)myrow * 128 + kc * 32 + quad * 8);
            xa = p[0];
            xb = p[1];
        }
        unsigned pk[4];
        pk[0] = (unsigned)f2bf(xa.x) | ((unsigned)f2bf(xa.y) << 16);
        pk[1] = (unsigned)f2bf(xa.z) | ((unsigned)f2bf(xa.w) << 16);
        pk[2] = (unsigned)f2bf(xb.x) | ((unsigned)f2bf(xb.y) << 16);
        pk[3] = (unsigned)f2bf(xb.z) | ((unsigned)f2bf(xb.w) << 16);
        short8 a;
        a[0] = (short)(pk[0] & 0xffff); a[1] = (short)(pk[0] >> 16);
        a[2] = (short)(pk[1] & 0xffff); a[3] = (short)(pk[1] >> 16);
        a[4] = (short)(pk[2] & 0xffff); a[5] = (short)(pk[2] >> 16);
        a[6] = (short)(pk[3] & 0xffff); a[7] = (short)(pk[3] >> 16);

        const short8* wb = (const short8*)wsW;
        short8 b0 = wb[(kc * 4 + 0) * 64 + lane];
        short8 b1 = wb[(kc * 4 + 1) * 64 + lane];
        short8 b2 = wb[(kc * 4 + 2) * 64 + lane];
        short8 b3 = wb[(kc * 4 + 3) * 64 + lane];

        acc0 = __builtin_amdgcn_mfma_f32_16x16x32_bf16(a, b0, acc0, 0, 0, 0);
        acc1 = __builtin_amdgcn_mfma_f32_16x16x32_bf16(a, b1, acc1, 0, 0, 0);
        acc2 = __builtin_amdgcn_mfma_f32_16x16x32_bf16(a, b2, acc2, 0, 0, 0);
        acc3 = __builtin_amdgcn_mfma_f32_16x16x32_bf16(a, b3, acc3, 0, 0, 0);
    }

    // C/D layout: col = lane&15, row = quad*4 + i  [m89-verified]
#pragma unroll
    for (int i = 0; i < 4; ++i) {
        int row = rowbase + quad * 4 + i;
        if (row < N) {
            long long o = (long long)row * 64 + n16;
            H[o]      = f2bf(acc0[i]);
            H[o + 16] = f2bf(acc1[i]);
            H[o + 32] = f2bf(acc2[i]);
            H[o + 48] = f2bf(acc3[i]);
        }
    }
}

// L2: H[N,32] = relu(Z[N,64]) @ W[64,32]; Z is packed bf16x2 (32 dwords/row); out bf16.

__global__ __launch_bounds__(256) void k_mm2(const unsigned* __restrict__ Z,
                                             const float* __restrict__ W,
                                             ushort_t* __restrict__ H, int N) {
    __shared__ float sW[64 * 32];  // 8 KB
    __shared__ float sX[64 * 64];  // 16 KB
    const int tid = threadIdx.x;
    for (int i = tid; i < 512; i += 256) ((float4*)sW)[i] = ((const float4*)W)[i];
    const long long row0 = (long long)blockIdx.x * 64;
    for (int i = tid; i < 2048; i += 256) {
        int r = i >> 5;         // local row
        int cp = i & 31;        // channel pair
        long long row = row0 + r;
        unsigned u = (row < N) ? Z[row * 32 + cp] : 0u;
        sX[r * 64 + 2 * cp]     = fmaxf(bf_lo(u), 0.f);
        sX[r * 64 + 2 * cp + 1] = fmaxf(bf_hi(u), 0.f);
    }
    __syncthreads();
    const int wv = tid >> 6, lane = tid & 63;
    const int c = lane & 31, hf = lane >> 5;
    const int rbase = wv * 16 + hf * 8;
    float acc[8] = {};
#pragma unroll 2
    for (int k = 0; k < 64; k += 4) {
        float4 xv[8];
#pragma unroll
        for (int r = 0; r < 8; ++r) xv[r] = *(const float4*)&sX[(rbase + r) * 64 + k];
        float w0 = sW[k * 32 + c];
        float w1 = sW[(k + 1) * 32 + c];
        float w2 = sW[(k + 2) * 32 + c];
        float w3 = sW[(k + 3) * 32 + c];
#pragma unroll
        for (int r = 0; r < 8; ++r)
            acc[r] += xv[r].x * w0 + xv[r].y * w1 + xv[r].z * w2 + xv[r].w * w3;
    }
#pragma unroll
    for (int r = 0; r < 8; ++r) {
        long long row = row0 + rbase + r;
        if (row < N) H[row * 32 + c] = f2bf(acc[r]);
    }
}

// ---------------- CSR aggregation: bf16 gather, fp32 accumulate ----------------
// Wave per dst row; preload (col,dis) into registers, shfl-broadcast.

// agg64: 32 lanes per edge (channel pairs), 2 edge groups.
__global__ __launch_bounds__(256) void k_agg64(const unsigned* __restrict__ h,
                                               const int* __restrict__ rowptr,
                                               const int* __restrict__ col,
                                               const float* __restrict__ dis,
                                               const float* __restrict__ b,
                                               unsigned* __restrict__ z, int N) {
    const int wave = (blockIdx.x * 256 + threadIdx.x) >> 6;
    const int lane = threadIdx.x & 63;
    if (wave >= N) return;
    const int row = wave;
    const int t = lane & 31, g = lane >> 5;
    const int start = rowptr[row];
    const int deg = rowptr[row + 1] - start;
    const float dr = dis[row];

    int myCol = row;
    float myDis = 0.f;
    if (lane < deg) {
        myCol = col[start + lane];
        myDis = dis[myCol];
    }

    unsigned us = h[row * 32 + t];  // self-loop (counted once via g==0)
    float w0s = g ? 0.f : dr;
    float ax = w0s * bf_lo(us), ay = w0s * bf_hi(us);

    const int cnt = min(deg, 64);
    for (int k0 = 0; k0 < cnt; k0 += 8) {
#pragma unroll
        for (int u = 0; u < 4; ++u) {
            int slot = k0 + 2 * u + g;
            int s = __shfl(myCol, slot);
            float w = __shfl(myDis, slot);
            unsigned uu = h[s * 32 + t];
            ax += w * bf_lo(uu);
            ay += w * bf_hi(uu);
        }
    }
    // rare tail: deg > 64
    for (int j = start + 64 + g; j < start + deg; j += 2) {
        int s = col[j];
        float w = dis[s];
        unsigned uu = h[s * 32 + t];
        ax += w * bf_lo(uu);
        ay += w * bf_hi(uu);
    }
    ax += __shfl_down(ax, 32);
    ay += __shfl_down(ay, 32);
    if (!g) {
        float2 bv = ((const float2*)b)[t];
        float ox = bv.x + dr * ax;
        float oy = bv.y + dr * ay;
        z[row * 32 + t] = (unsigned)f2bf(ox) | ((unsigned)f2bf(oy) << 16);
    }
}

// agg32: 16 lanes per edge (channel pairs), 4 edge groups; fp32 output (final).
__global__ __launch_bounds__(256) void k_agg32(const unsigned* __restrict__ h,
                                               const int* __restrict__ rowptr,
                                               const int* __restrict__ col,
                                               const float* __restrict__ dis,
                                               const float* __restrict__ b,
                                               float* __restrict__ out, int N) {
    const int wave = (blockIdx.x * 256 + threadIdx.x) >> 6;
    const int lane = threadIdx.x & 63;
    if (wave >= N) return;
    const int row = wave;
    const int t = lane & 15, g = lane >> 4;
    const int start = rowptr[row];
    const int deg = rowptr[row + 1] - start;
    const float dr = dis[row];

    int myCol = row;
    float myDis = 0.f;
    if (lane < deg) {
        myCol = col[start + lane];
        myDis = dis[myCol];
    }

    unsigned us = h[row * 16 + t];
    float w0s = g ? 0.f : dr;
    float ax = w0s * bf_lo(us), ay = w0s * bf_hi(us);

    const int cnt = min(deg, 64);
    for (int k0 = 0; k0 < cnt; k0 += 16) {
#pragma unroll
        for (int u = 0; u < 4; ++u) {
            int slot = k0 + 4 * u + g;
            int s = __shfl(myCol, slot);
            float w = __shfl(myDis, slot);
            unsigned uu = h[s * 16 + t];
            ax += w * bf_lo(uu);
            ay += w * bf_hi(uu);
        }
    }
    for (int j = start + 64 + g; j < start + deg; j += 4) {
        int s = col[j];
        float w = dis[s];
        unsigned uu = h[s * 16 + t];
        ax += w * bf_lo(uu);
        ay += w * bf_hi(uu);
    }
    ax += __shfl_down(ax, 32);
    ay += __shfl_down(ay, 32);
    ax += __shfl_down(ax, 16);
    ay += __shfl_down(ay, 16);
    if (!g) {
        float2 bv = ((const float2*)b)[t];
        float2 o;
        o.x = bv.x + dr * ax;
        o.y = bv.y + dr * ay;
        ((float2*)out)[row * 16 + t] = o;
    }
}

extern "C" void kernel_launch(void* const* d_in, const int* in_sizes, int n_in,
                              void* d_out, int out_size, void* d_ws, size_t ws_size,
                              hipStream_t stream) {
    const float* x  = (const float*)d_in[0];
    const int*   ei = (const int*)d_in[1];
    const float* W1 = (const float*)d_in[2];
    const float* b1 = (const float*)d_in[3];
    const float* W2 = (const float*)d_in[4];
    const float* b2 = (const float*)d_in[5];
    float* out = (float*)d_out;

    const int N = in_sizes[0] / IN_CH;
    const int E = in_sizes[1] / 2;
    const int* esrc = ei;
    const int* edst = ei + E;

    int nbk = (N + 255) >> 8;
    if (nbk > MAXB) nbk = MAXB;
    const int per_b = (E + nbk - 1) / nbk;
    const int cap = per_b + per_b / 4 + 256;  // ~20-sigma headroom

    // workspace layout (4-byte units, regions padded to 16)
    int* rowptr   = (int*)d_ws;                          // N+1
    int* gcursor  = rowptr + (((N + 1) + 15) & ~15);     // MAXB
    int* bbase    = gcursor + MAXB;                      // MAXB
    unsigned* wsW = (unsigned*)(bbase + MAXB);           // 4096 dwords (b-frag repack)
    int* col      = (int*)(wsW + 4096);                  // E
    float* dis    = (float*)(col + ((E + 15) & ~15));    // N
    ushort_t* h1  = (ushort_t*)(dis + ((N + 15) & ~15)); // N*64 bf16
    unsigned* z1  = (unsigned*)(h1 + (((long long)N * 64 + 31) & ~31LL)); // N*32 dwords (bf16x2)
    unsigned* pairs = z1;             // nbk*cap dwords (~8.4MB) <= N*32 dwords (12.8MB), dead before agg64
    ushort_t* h2  = h1;               // h1 dead after agg64

    const int B = 256;

    hipMemsetAsync(gcursor, 0, MAXB * sizeof(int), stream);
    k_prepW<<<4, B, 0, stream>>>(W1, wsW);
    k_partition<<<(E + EPB - 1) / EPB, B, 0, stream>>>(esrc, edst, gcursor, pairs, E, nbk, cap);
    k_bscan<<<1, 512, 0, stream>>>(gcursor, bbase, rowptr, nbk, cap, N);
    k_bucket_build<<<nbk, B, 0, stream>>>(pairs, gcursor, bbase, rowptr, col, dis, cap, N);

    k_mm1<<<(N + 63) / 64, B, 0, stream>>>(x, wsW, h1, N);
    k_agg64<<<((long long)N * 64 + B - 1) / B, B, 0, stream>>>((const unsigned*)h1, rowptr, col, dis, b1, z1, N);

    k_mm2<<<(N + 63) / 64, B, 0, stream>>>(z1, W2, h2, N);
    k_agg32<<<((long long)N * 64 + B - 1) / B, B, 0, stream>>>((const unsigned*)h2, rowptr, col, dis, b2, out, N);
}

// Round 7
// 251.790 us; speedup vs baseline: 3.2395x; 1.0387x over previous
//
#include <hip/hip_runtime.h>
#include <hip/hip_bf16.h>

#define IN_CH 128
#define HID_CH 64
#define OUT_CH 32
#define EPB 2048  // edges per partition block
#define MAXB 512  // max buckets (N <= 131072)

typedef unsigned short ushort_t;
typedef __attribute__((ext_vector_type(8))) short short8;
typedef __attribute__((ext_vector_type(4))) float float4v;

static __device__ __forceinline__ ushort_t f2bf(float f) {
    unsigned u = __float_as_uint(f);
    unsigned r = (u + 0x7fff + ((u >> 16) & 1)) >> 16;  // RNE
    return (ushort_t)r;
}
static __device__ __forceinline__ float bf_lo(unsigned u) { return __uint_as_float(u << 16); }
static __device__ __forceinline__ float bf_hi(unsigned u) { return __uint_as_float(u & 0xffff0000u); }

// ---------------- single-pass radix partition by dst>>8 ----------------

__global__ __launch_bounds__(256) void k_partition(const int* __restrict__ src,
                                                   const int* __restrict__ dst,
                                                   int* __restrict__ gcursor,
                                                   unsigned* __restrict__ pairs,
                                                   int E, int nbk, int cap) {
    __shared__ int lhist[MAXB];
    __shared__ int lbase[MAXB];
    __shared__ int lcur[MAXB];
    const int tid = threadIdx.x;
    for (int b = tid; b < nbk; b += 256) { lhist[b] = 0; lcur[b] = 0; }
    __syncthreads();
    int s[8], d[8];
    const int e0 = blockIdx.x * EPB;
#pragma unroll
    for (int j = 0; j < 8; ++j) {
        int e = e0 + j * 256 + tid;
        if (e < E) {
            s[j] = src[e];
            d[j] = dst[e];
            atomicAdd(&lhist[d[j] >> 8], 1);
        } else {
            d[j] = -1;
        }
    }
    __syncthreads();
    for (int b = tid; b < nbk; b += 256)
        lbase[b] = lhist[b] ? atomicAdd(&gcursor[b], lhist[b]) : 0;
    __syncthreads();
#pragma unroll
    for (int j = 0; j < 8; ++j) {
        if (d[j] >= 0) {
            int b = d[j] >> 8;
            int loc = atomicAdd(&lcur[b], 1);
            int idx = lbase[b] + loc;
            if (idx < cap)
                pairs[(long long)b * cap + idx] = ((unsigned)s[j] << 8) | (unsigned)(d[j] & 255);
        }
    }
}

// exclusive scan over bucket totals (nbk <= 512); also writes rowptr[N] = grand total
__global__ __launch_bounds__(512) void k_bscan(const int* __restrict__ gcursor,
                                               int* __restrict__ bbase,
                                               int* __restrict__ rowptr,
                                               int nbk, int cap, int N) {
    __shared__ int s[512];
    const int tid = threadIdx.x;
    int v = (tid < nbk) ? min(gcursor[tid], cap) : 0;
    s[tid] = v;
    __syncthreads();
    for (int off = 1; off < 512; off <<= 1) {
        int val = (tid >= off) ? s[tid - off] : 0;
        __syncthreads();
        s[tid] += val;
        __syncthreads();
    }
    if (tid < nbk) bbase[tid] = s[tid] - v;
    if (tid == nbk - 1) rowptr[N] = s[tid];
}

// fused per-bucket: row counts -> LDS scan -> rowptr + dis -> direct col placement
__global__ __launch_bounds__(256) void k_bucket_build(const unsigned* __restrict__ pairs,
                                                      const int* __restrict__ gcursor,
                                                      const int* __restrict__ bbase,
                                                      int* __restrict__ rowptr,
                                                      int* __restrict__ col,
                                                      float* __restrict__ dis,
                                                      int cap, int N) {
    __shared__ int lc[256];
    __shared__ int ls[256];
    __shared__ int lcur[256];
    const int b = blockIdx.x, tid = threadIdx.x;
    lc[tid] = 0;
    __syncthreads();
    const int cnt = min(gcursor[b], cap);
    const int base = bbase[b];
    const unsigned* p = pairs + (long long)b * cap;
    for (int i = tid; i < cnt; i += 256) atomicAdd(&lc[p[i] & 255], 1);
    __syncthreads();
    const int v = lc[tid];
    ls[tid] = v;
    __syncthreads();
    for (int off = 1; off < 256; off <<= 1) {
        int val = (tid >= off) ? ls[tid - off] : 0;
        __syncthreads();
        ls[tid] += val;
        __syncthreads();
    }
    const int excl = ls[tid] - v;
    const int row = b * 256 + tid;
    if (row < N) {
        rowptr[row] = base + excl;
        dis[row] = rsqrtf((float)(v + 1));  // +1 self-loop
    }
    lcur[tid] = base + excl;
    __syncthreads();
    for (int i = tid; i < cnt; i += 256) {
        unsigned pk = p[i];
        int pos = atomicAdd(&lcur[pk & 255], 1);
        col[pos] = (int)(pk >> 8);
    }
}

// ---------------- W1 -> b-fragment repack (bf16) + gcursor zero ----------------

__global__ __launch_bounds__(256) void k_prepW(const float* __restrict__ W,
                                               unsigned* __restrict__ wsW,
                                               int* __restrict__ gcursor) {
    int s = blockIdx.x * 256 + threadIdx.x;
    if (s < MAXB) gcursor[s] = 0;
    if (s >= 1024) return;
    int lane = s & 63;
    int nt = (s >> 6) & 3;
    int kc = s >> 8;
    int c = nt * 16 + (lane & 15);
    int k0 = kc * 32 + (lane >> 4) * 8;
    unsigned o[4];
#pragma unroll
    for (int d = 0; d < 4; ++d) {
        unsigned lo = f2bf(W[(k0 + 2 * d) * 64 + c]);
        unsigned hi = f2bf(W[(k0 + 2 * d + 1) * 64 + c]);
        o[d] = lo | (hi << 16);
    }
    ((uint4*)wsW)[s] = make_uint4(o[0], o[1], o[2], o[3]);
}

// ---------------- L1 matmul via MFMA (unchanged from R6) ----------------

__global__ __launch_bounds__(256) void k_mm1(const float* __restrict__ X,
                                             const unsigned* __restrict__ wsW,
                                             ushort_t* __restrict__ H, int N) {
    const int tid = threadIdx.x;
    const int wv = tid >> 6, lane = tid & 63;
    const int quad = lane >> 4, n16 = lane & 15;
    const int rowbase = blockIdx.x * 64 + wv * 16;
    const int myrow = rowbase + n16;
    const bool rok = (myrow < N);

    float4v acc0 = {}, acc1 = {}, acc2 = {}, acc3 = {};

#pragma unroll
    for (int kc = 0; kc < 4; ++kc) {
        float4 xa = make_float4(0.f, 0.f, 0.f, 0.f), xb = xa;
        if (rok) {
            const float4* p = (const float4*)(X + (long long)myrow * 128 + kc * 32 + quad * 8);
            xa = p[0];
            xb = p[1];
        }
        unsigned pk[4];
        pk[0] = (unsigned)f2bf(xa.x) | ((unsigned)f2bf(xa.y) << 16);
        pk[1] = (unsigned)f2bf(xa.z) | ((unsigned)f2bf(xa.w) << 16);
        pk[2] = (unsigned)f2bf(xb.x) | ((unsigned)f2bf(xb.y) << 16);
        pk[3] = (unsigned)f2bf(xb.z) | ((unsigned)f2bf(xb.w) << 16);
        short8 a;
        a[0] = (short)(pk[0] & 0xffff); a[1] = (short)(pk[0] >> 16);
        a[2] = (short)(pk[1] & 0xffff); a[3] = (short)(pk[1] >> 16);
        a[4] = (short)(pk[2] & 0xffff); a[5] = (short)(pk[2] >> 16);
        a[6] = (short)(pk[3] & 0xffff); a[7] = (short)(pk[3] >> 16);

        const short8* wb = (const short8*)wsW;
        short8 b0 = wb[(kc * 4 + 0) * 64 + lane];
        short8 b1 = wb[(kc * 4 + 1) * 64 + lane];
        short8 b2 = wb[(kc * 4 + 2) * 64 + lane];
        short8 b3 = wb[(kc * 4 + 3) * 64 + lane];

        acc0 = __builtin_amdgcn_mfma_f32_16x16x32_bf16(a, b0, acc0, 0, 0, 0);
        acc1 = __builtin_amdgcn_mfma_f32_16x16x32_bf16(a, b1, acc1, 0, 0, 0);
        acc2 = __builtin_amdgcn_mfma_f32_16x16x32_bf16(a, b2, acc2, 0, 0, 0);
        acc3 = __builtin_amdgcn_mfma_f32_16x16x32_bf16(a, b3, acc3, 0, 0, 0);
    }

#pragma unroll
    for (int i = 0; i < 4; ++i) {
        int row = rowbase + quad * 4 + i;
        if (row < N) {
            long long o = (long long)row * 64 + n16;
            H[o]      = f2bf(acc0[i]);
            H[o + 16] = f2bf(acc1[i]);
            H[o + 32] = f2bf(acc2[i]);
            H[o + 48] = f2bf(acc3[i]);
        }
    }
}

// ---------------- fused agg64 + mm2: h2 = relu(b1 + D A D h1) @ W2 ----------------
// Grid-stride: each wave handles ~8 rows; W2 slice lives in registers (amortized).
// Per row: gather-reduce z (fp32, never materialized), LDS z-row exchange, dot, bf16 out.

__global__ __launch_bounds__(256) void k_agg64_mm2(const unsigned* __restrict__ h,
                                                   const int* __restrict__ rowptr,
                                                   const int* __restrict__ col,
                                                   const float* __restrict__ dis,
                                                   const float* __restrict__ b1,
                                                   const float* __restrict__ W2,
                                                   unsigned* __restrict__ h2, int N) {
    __shared__ float zbuf[4][64];
    const int wv = threadIdx.x >> 6, lane = threadIdx.x & 63;
    const int t = lane & 31, g = lane >> 5;  // channel-pair t, edge group / k-half g

    // W2 register slice: w[k] = W2[(g*32+k)*32 + t]  (lane covers out-ch t, k-half g)
    float w[32];
#pragma unroll
    for (int k = 0; k < 32; ++k) w[k] = W2[(g * 32 + k) * 32 + t];
    const float2 bv = ((const float2*)b1)[t];  // b1 pair for channels 2t,2t+1

    const int wave0 = blockIdx.x * 4 + wv;
    const int nwaves = gridDim.x * 4;

    for (int row = wave0; row < N; row += nwaves) {
        const int start = rowptr[row];
        const int deg = rowptr[row + 1] - start;
        const float dr = dis[row];

        int myCol = row;
        float myDis = 0.f;
        if (lane < deg) {
            myCol = col[start + lane];
            myDis = dis[myCol];
        }

        unsigned us = h[row * 32 + t];  // self-loop (g==0 only)
        float w0s = g ? 0.f : dr;
        float ax = w0s * bf_lo(us), ay = w0s * bf_hi(us);

        const int cnt = min(deg, 64);
        for (int k0 = 0; k0 < cnt; k0 += 16) {  // 8 independent gathers/lane/iter
#pragma unroll
            for (int u = 0; u < 8; ++u) {
                int slot = k0 + 2 * u + g;
                int s = __shfl(myCol, slot);
                float ww = __shfl(myDis, slot);
                unsigned uu = h[s * 32 + t];
                ax += ww * bf_lo(uu);
                ay += ww * bf_hi(uu);
            }
        }
        for (int j = start + 64 + g; j < start + deg; j += 2) {  // rare tail
            int s = col[j];
            float ww = dis[s];
            unsigned uu = h[s * 32 + t];
            ax += ww * bf_lo(uu);
            ay += ww * bf_hi(uu);
        }
        ax += __shfl_down(ax, 32);
        ay += __shfl_down(ay, 32);

        // lanes g==0 hold z channels (2t, 2t+1); stage full z-row in LDS
        if (!g) {
            float2 zv;
            zv.x = bv.x + dr * ax;
            zv.y = bv.y + dr * ay;
            *(float2*)&zbuf[wv][2 * t] = zv;
        }
        __builtin_amdgcn_wave_barrier();  // keep compiler from hoisting reads above write

        // dot: lane computes out-ch t over k-half g
        float acc = 0.f;
        const float* zp = &zbuf[wv][g * 32];
#pragma unroll
        for (int k = 0; k < 32; k += 4) {
            float4 zv = *(const float4*)(zp + k);
            acc += fmaxf(zv.x, 0.f) * w[k] + fmaxf(zv.y, 0.f) * w[k + 1] +
                   fmaxf(zv.z, 0.f) * w[k + 2] + fmaxf(zv.w, 0.f) * w[k + 3];
        }
        __builtin_amdgcn_wave_barrier();  // reads done before next iter's write
        acc += __shfl_down(acc, 32);      // lane c<32: out channel c

        float o0 = __shfl(acc, 2 * t);
        float o1 = __shfl(acc, 2 * t + 1);
        if (lane < 16)
            h2[row * 16 + lane] = (unsigned)f2bf(o0) | ((unsigned)f2bf(o1) << 16);
    }
}

// ---------------- agg32: final layer aggregation (fp32 out) ----------------

__global__ __launch_bounds__(256) void k_agg32(const unsigned* __restrict__ h,
                                               const int* __restrict__ rowptr,
                                               const int* __restrict__ col,
                                               const float* __restrict__ dis,
                                               const float* __restrict__ b,
                                               float* __restrict__ out, int N) {
    const int wave = (blockIdx.x * 256 + threadIdx.x) >> 6;
    const int lane = threadIdx.x & 63;
    if (wave >= N) return;
    const int row = wave;
    const int t = lane & 15, g = lane >> 4;
    const int start = rowptr[row];
    const int deg = rowptr[row + 1] - start;
    const float dr = dis[row];

    int myCol = row;
    float myDis = 0.f;
    if (lane < deg) {
        myCol = col[start + lane];
        myDis = dis[myCol];
    }

    unsigned us = h[row * 16 + t];
    float w0s = (g == 0) ? dr : 0.f;
    float ax = w0s * bf_lo(us), ay = w0s * bf_hi(us);

    const int cnt = min(deg, 64);
    for (int k0 = 0; k0 < cnt; k0 += 32) {  // 8 independent gathers/lane/iter
#pragma unroll
        for (int u = 0; u < 8; ++u) {
            int slot = k0 + 4 * u + g;
            int s = __shfl(myCol, slot);
            float w = __shfl(myDis, slot);
            unsigned uu = h[s * 16 + t];
            ax += w * bf_lo(uu);
            ay += w * bf_hi(uu);
        }
    }
    for (int j = start + 64 + g; j < start + deg; j += 4) {
        int s = col[j];
        float w = dis[s];
        unsigned uu = h[s * 16 + t];
        ax += w * bf_lo(uu);
        ay += w * bf_hi(uu);
    }
    ax += __shfl_down(ax, 32);
    ay += __shfl_down(ay, 32);
    ax += __shfl_down(ax, 16);
    ay += __shfl_down(ay, 16);
    if (!g) {
        float2 bv = ((const float2*)b)[t];
        float2 o;
        o.x = bv.x + dr * ax;
        o.y = bv.y + dr * ay;
        ((float2*)out)[row * 16 + t] = o;
    }
}

extern "C" void kernel_launch(void* const* d_in, const int* in_sizes, int n_in,
                              void* d_out, int out_size, void* d_ws, size_t ws_size,
                              hipStream_t stream) {
    const float* x  = (const float*)d_in[0];
    const int*   ei = (const int*)d_in[1];
    const float* W1 = (const float*)d_in[2];
    const float* b1 = (const float*)d_in[3];
    const float* W2 = (const float*)d_in[4];
    const float* b2 = (const float*)d_in[5];
    float* out = (float*)d_out;

    const int N = in_sizes[0] / IN_CH;
    const int E = in_sizes[1] / 2;
    const int* esrc = ei;
    const int* edst = ei + E;

    int nbk = (N + 255) >> 8;
    if (nbk > MAXB) nbk = MAXB;
    const int per_b = (E + nbk - 1) / nbk;
    const int cap = per_b + per_b / 4 + 256;  // ~20-sigma headroom

    // workspace layout (4-byte units, regions padded to 16)
    int* rowptr   = (int*)d_ws;                          // N+1
    int* gcursor  = rowptr + (((N + 1) + 15) & ~15);     // MAXB
    int* bbase    = gcursor + MAXB;                      // MAXB
    unsigned* wsW = (unsigned*)(bbase + MAXB);           // 4096 dwords (b-frag repack)
    int* col      = (int*)(wsW + 4096);                  // E
    float* dis    = (float*)(col + ((E + 15) & ~15));    // N
    ushort_t* h1  = (ushort_t*)(dis + ((N + 15) & ~15)); // N*64 bf16
    unsigned* scratch = (unsigned*)(h1 + (((long long)N * 64 + 31) & ~31LL));
    unsigned* pairs = scratch;        // nbk*cap dwords (~8.4MB), dead after bucket_build
    unsigned* h2    = scratch;        // N*16 dwords (6.4MB) bf16x2, written after pairs dead

    const int B = 256;

    k_prepW<<<4, B, 0, stream>>>(W1, wsW, gcursor);
    k_partition<<<(E + EPB - 1) / EPB, B, 0, stream>>>(esrc, edst, gcursor, pairs, E, nbk, cap);
    k_bscan<<<1, 512, 0, stream>>>(gcursor, bbase, rowptr, nbk, cap, N);
    k_bucket_build<<<nbk, B, 0, stream>>>(pairs, gcursor, bbase, rowptr, col, dis, cap, N);

    k_mm1<<<(N + 63) / 64, B, 0, stream>>>(x, wsW, h1, N);

    // fused layer-1 aggregation + layer-2 transform (~8 rows per wave)
    const int fblocks = (N + 31) / 32;
    k_agg64_mm2<<<fblocks, B, 0, stream>>>((const unsigned*)h1, rowptr, col, dis, b1, W2, h2, N);

    k_agg32<<<((long long)N * 64 + B - 1) / B, B, 0, stream>>>((const unsigned*)h2, rowptr, col, dis, b2, out, N);
}